// Round 2
// baseline (63.627 us; speedup 1.0000x reference)
//
#include <hip/hip_runtime.h>
#include <hip/hip_bf16.h>

// out[8192,64] = L[8192,8192] (fp32) @ M[8192,64] (fp32)
// A: direct global->VGPR fragment loads (2-step prefetch, never drained at barriers).
// B: bf16 transpose-staged in double-buffered LDS (2x8KB), raw s_barrier + lgkmcnt(0) only.
// Split-K=8 with fp32 atomics.

#define NPED 8192
#define HID  64
#define BM   64
#define BK   64
#define KSPLIT 8
#define KRANGE (NPED / KSPLIT)   // 1024
#define NSTEPS (KRANGE / BK)     // 16

typedef __bf16 bf16x8 __attribute__((ext_vector_type(8)));
typedef float  f32x4  __attribute__((ext_vector_type(4)));
typedef unsigned short u16;
typedef u16 u16x8 __attribute__((ext_vector_type(8)));

// swizzled LDS byte offset for [row][kbyte], 128 B per row (T2-style XOR swizzle)
__device__ __forceinline__ int swz(int row, int kbyte) {
    return (row << 7) + (kbyte ^ ((row & 7) << 4));
}

__device__ __forceinline__ bf16x8 cvt8(float4 lo, float4 hi) {
    bf16x8 r;
    r[0] = (__bf16)lo.x; r[1] = (__bf16)lo.y; r[2] = (__bf16)lo.z; r[3] = (__bf16)lo.w;
    r[4] = (__bf16)hi.x; r[5] = (__bf16)hi.y; r[6] = (__bf16)hi.z; r[7] = (__bf16)hi.w;
    return r;
}

__global__ __launch_bounds__(256, 4)
void crowd_mm(const float* __restrict__ A, const float* __restrict__ B,
              float* __restrict__ out)
{
    __shared__ u16 Bs[2][HID * BK];   // [h][k] bf16, swizzled; 8 KB each

    const int tid  = threadIdx.x;
    const int lane = tid & 63;
    const int w    = tid >> 6;        // wave 0..3, owns rows w*16..w*16+15
    const int rb   = blockIdx.x;
    const int ks   = blockIdx.y;
    const long kb  = (long)ks * KRANGE;

    const int l15 = lane & 15;
    const int l4  = lane >> 4;

    // A fragment-direct addressing: lane l -> row (l&15), k = (l>>4)*8 + [0..7] (+ s*32)
    const float* Ap = A + (long)(rb * BM + w * 16 + l15) * NPED + kb + l4 * 8;

    // B staging: thread covers h = lane, k = w*16 + [0..15]
    const float* Bp = B + (kb + w * 16) * HID + lane;

    float4 abuf[2][4];     // [buf][quad]: quads 0,1 -> s=0 ; 2,3 -> s=1
    float  bbuf[2][16];
    f32x4  acc[4] = {};

    auto load_a = [&](int buf, int step) {
        const float* p = Ap + step * BK;
        abuf[buf][0] = *(const float4*)(p);
        abuf[buf][1] = *(const float4*)(p + 4);
        abuf[buf][2] = *(const float4*)(p + 32);
        abuf[buf][3] = *(const float4*)(p + 36);
    };
    auto load_b = [&](int buf, int step) {
        const float* p = Bp + step * (BK * HID);
        #pragma unroll
        for (int j = 0; j < 16; ++j) bbuf[buf][j] = p[j * HID];
    };
    auto stage_b = [&](int buf) {   // bbuf[buf] (= B tile 'buf' parity) -> Bs[buf]
        u16x8 lo, hi;
        #pragma unroll
        for (int j = 0; j < 8; ++j) {
            __bf16 x = (__bf16)bbuf[buf][j];
            __bf16 y = (__bf16)bbuf[buf][j + 8];
            lo[j] = __builtin_bit_cast(u16, x);
            hi[j] = __builtin_bit_cast(u16, y);
        }
        char* base = (char*)&Bs[buf][0];
        const int kbyte = w * 32;
        *(u16x8*)(base + swz(lane, kbyte))      = lo;
        *(u16x8*)(base + swz(lane, kbyte + 16)) = hi;
    };
    auto compute = [&](int buf, bf16x8 afr0, bf16x8 afr1) {
        const char* base = (const char*)&Bs[buf][0];
        #pragma unroll
        for (int s = 0; s < 2; ++s) {
            const bf16x8 afr = s ? afr1 : afr0;
            const int kbyte = s * 64 + l4 * 16;
            #pragma unroll
            for (int t = 0; t < 4; ++t) {
                bf16x8 bfr = *(const bf16x8*)(base + swz(t * 16 + l15, kbyte));
                acc[t] = __builtin_amdgcn_mfma_f32_16x16x32_bf16(afr, bfr, acc[t], 0, 0, 0);
            }
        }
    };

    // Prologue: 2 steps in flight, B(0) staged.
    load_a(0, 0); load_b(0, 0);
    load_a(1, 1); load_b(1, 1);
    stage_b(0);
    asm volatile("s_waitcnt lgkmcnt(0)" ::: "memory");
    __builtin_amdgcn_s_barrier();

    #pragma unroll
    for (int step = 0; step < NSTEPS; ++step) {
        const int cur = step & 1, nxt = cur ^ 1;
        // consume A(step) regs before overwrite
        bf16x8 afr0 = cvt8(abuf[cur][0], abuf[cur][1]);
        bf16x8 afr1 = cvt8(abuf[cur][2], abuf[cur][3]);
        // prefetch step+2 (loads stay in flight across the raw barrier — no vmcnt drain)
        if (step + 2 < NSTEPS) { load_a(cur, step + 2); load_b(cur, step + 2); }
        // stage B(step+1) into the other LDS buffer
        if (step + 1 < NSTEPS) stage_b(nxt);
        // MFMA on current tile
        compute(cur, afr0, afr1);
        // drain LDS ops only, then barrier (writes visible, reads done before next overwrite)
        asm volatile("s_waitcnt lgkmcnt(0)" ::: "memory");
        __builtin_amdgcn_s_barrier();
    }

    // Epilogue: C/D layout col = lane&15, row = (lane>>4)*4 + reg
    #pragma unroll
    for (int t = 0; t < 4; ++t) {
        #pragma unroll
        for (int r = 0; r < 4; ++r) {
            int row = rb * BM + w * 16 + l4 * 4 + r;
            int col = t * 16 + l15;
            atomicAdd(&out[row * HID + col], acc[t][r]);
        }
    }
}

extern "C" void kernel_launch(void* const* d_in, const int* in_sizes, int n_in,
                              void* d_out, int out_size, void* d_ws, size_t ws_size,
                              hipStream_t stream) {
    const float* A = (const float*)d_in[0];   // location_data [8192, 8192]
    const float* B = (const float*)d_in[1];   // motion_data   [8192, 64]
    float* out = (float*)d_out;               // [8192, 64]

    hipMemsetAsync(d_out, 0, (size_t)out_size * sizeof(float), stream);

    dim3 grid(NPED / BM, KSPLIT);
    crowd_mm<<<grid, 256, 0, stream>>>(A, B, out);
}